// Round 2
// baseline (313.173 us; speedup 1.0000x reference)
//
#include <hip/hip_runtime.h>
#include <hip/hip_cooperative_groups.h>
#include <math.h>

namespace cg = cooperative_groups;

#define Dm   768
#define Hm   64
#define SEQ  4096
#define NB   4
#define NROW (NB * SEQ)

// scale 1/sqrt(64) and log2(e) folded into Wq at wconv time -> exp2 domain
#define QSCALE (0.125f * 1.4426950408889634f)

typedef _Float16 f16;
typedef __attribute__((ext_vector_type(8))) _Float16 f16x8;
typedef __attribute__((ext_vector_type(2))) __fp16 fp16x2_raw;
typedef __attribute__((ext_vector_type(4))) float f32x4;
typedef unsigned int uint;
typedef unsigned short ushort;

#define MFMAH(A, B, C) __builtin_amdgcn_mfma_f32_16x16x32_f16(A, B, C, 0, 0, 0)

__device__ __forceinline__ uint pkrtz(float a, float b) {
    fp16x2_raw r = __builtin_amdgcn_cvt_pkrtz(a, b);
    return __builtin_bit_cast(uint, r);
}
__device__ __forceinline__ ushort f2h(float f) {
    f16 h = (f16)f;
    return __builtin_bit_cast(ushort, h);
}
union F16x8U { uint u[4]; f16x8 v; };

// ---------------------------------------------------------------------------
// Single cooperative kernel: wconv -> grid.sync -> proj -> grid.sync -> attn.
// 256 blocks x 512 threads, 1 block/CU (84KB LDS), all blocks co-resident.
// Removes two kernel-launch gaps and keeps Q/K/V L2-warm into attn; also
// makes the whole workload ONE dispatch so rocprof counters become visible.
//
// Phase 1 (proj): 64 rows/block, 8 waves = 4 row-groups x 2-way split-K.
// Wave (g, kh): rows [bb*64+g*16, +16), K in [kh*384, +384) = 12 iters of 32.
// B frags from L2-hot WTt (single-buffered); A ix fp32 ring-3 distance-2
// register prefetch. 2-way combine through LDS (48KB), kh==0 wave stores.
//
// Phase 2 (attn): unchanged flash structure. 64 queries/block; wave w owns
// j in [w*512,+512) = 16 iters of 32 keys; K/V ring-3 register prefetch;
// PV lags QK by one iter via double-buffered LDS P strips; no-max exp2
// softmax; 8-way tree combine (rows padded to 68 floats = 2-way banks).
// ---------------------------------------------------------------------------
#define OSTR 68
#define OBUF 4352   // 64 rows * 68 floats per combine buffer

__global__ __launch_bounds__(512, 2) void fused(
    const float* __restrict__ ix,
    const float* __restrict__ Wq, const float* __restrict__ Wk,
    const float* __restrict__ Wv,
    ushort* __restrict__ WTt,
    ushort* __restrict__ Qw, ushort* __restrict__ Kt, ushort* __restrict__ Vt,
    float* __restrict__ out)
{
    // floats [0,17408): attn combine bufs (4 x 4352), aliased by P strips
    // during the attn loop and by the proj combine (12288 floats) in phase 1.
    // floats [20480,20992): l per wave.
    __shared__ __align__(16) float aF[20992];   // 83968 B
    short* aS = (short*)aF;

    cg::grid_group grid = cg::this_grid();

    const int t    = threadIdx.x;
    const int lane = t & 63;
    const int w    = __builtin_amdgcn_readfirstlane(t >> 6);
    const int q15  = lane & 15, quad = lane >> 4;
    const int bb   = blockIdx.x;

    // ================= phase 0: wconv =================
    // W -> WTt f16, tiled [kt(24)][c(192)][kk(32)]. c: 0-63 Q (QSCALE
    // folded), 64-127 K, 128-191 V. Blocks 192..255 idle here.
    if (bb < 192) {
        const int c   = bb;
        const int mat = c >> 6, col = c & 63;
        const float* W = (mat == 0) ? Wq : (mat == 1 ? Wk : Wv);
        const float sc = (mat == 0) ? QSCALE : 1.0f;
        for (int k = t; k < Dm; k += 512)
            WTt[((size_t)(k >> 5) * 192 + c) * 32 + (k & 31)] = f2h(W[k * 64 + col] * sc);
    }
    __threadfence();
    grid.sync();

    // ================= phase 1: proj =================
    {
        const int g   = w >> 1;       // row group 0..3
        const int kh  = w & 1;        // split-K half
        const int gr0 = bb * 64 + g * 16;

        const float*  Ab = ix + (size_t)(gr0 + q15) * Dm + kh * 384 + quad * 8;
        const ushort* Bb = WTt + ((size_t)(kh * 12) * 192 + q15) * 32 + quad * 8;

        f32x4 acc[12];
#pragma unroll
        for (int ct = 0; ct < 12; ++ct) acc[ct] = (f32x4){0.f, 0.f, 0.f, 0.f};

        f32x4 Af[3][2];   // ring-3, distance-2
#pragma unroll
        for (int i = 0; i < 2; ++i) {
            Af[i][0] = *(const f32x4*)(Ab + i * 32);
            Af[i][1] = *(const f32x4*)(Ab + i * 32 + 4);
        }

#pragma unroll
        for (int it = 0; it < 12; ++it) {
            // B loads first (L2-hot, single buffer, one live set)
            f16x8 Bf[12];
#pragma unroll
            for (int ct = 0; ct < 12; ++ct)
                Bf[ct] = *(const f16x8*)(Bb + (size_t)it * 6144 + ct * 512);

            if (it + 2 < 12) {
                Af[(it + 2) % 3][0] = *(const f32x4*)(Ab + (it + 2) * 32);
                Af[(it + 2) % 3][1] = *(const f32x4*)(Ab + (it + 2) * 32 + 4);
            }

            F16x8U af;
            af.u[0] = pkrtz(Af[it % 3][0].x, Af[it % 3][0].y);
            af.u[1] = pkrtz(Af[it % 3][0].z, Af[it % 3][0].w);
            af.u[2] = pkrtz(Af[it % 3][1].x, Af[it % 3][1].y);
            af.u[3] = pkrtz(Af[it % 3][1].z, Af[it % 3][1].w);
            __builtin_amdgcn_s_setprio(1);
#pragma unroll
            for (int ct = 0; ct < 12; ++ct)
                acc[ct] = MFMAH(af.v, Bf[ct], acc[ct]);
            __builtin_amdgcn_s_setprio(0);
        }

        // ---- 2-way split-K combine through LDS; kh==0 stores ----
        float* cb = aF + g * 3072;
        if (kh == 1) {
#pragma unroll
            for (int ct = 0; ct < 12; ++ct)
                *(f32x4*)&cb[(ct * 64 + lane) * 4] = acc[ct];
        }
        __syncthreads();
        if (kh == 0) {
#pragma unroll
            for (int ct = 0; ct < 12; ++ct) {
                f32x4 o = *(const f32x4*)&cb[(ct * 64 + lane) * 4];
                acc[ct].x += o.x; acc[ct].y += o.y; acc[ct].z += o.z; acc[ct].w += o.w;
            }
            const int h16 = (gr0 >> 4) & 1;
            const int n4  = gr0 >> 4;
            const int j32 = gr0 >> 5;
#pragma unroll
            for (int ct = 0; ct < 12; ++ct) {
                float vals[4] = {acc[ct].x, acc[ct].y, acc[ct].z, acc[ct].w};
                if (ct < 4) {                       // Q: row-major, 32B runs
#pragma unroll
                    for (int r = 0; r < 4; ++r)
                        Qw[(size_t)(gr0 + quad * 4 + r) * 64 + ct * 16 + q15] = f2h(vals[r]);
                } else if (ct < 8) {                // K tiled: [j>>4][k>>4][j&15][k&15]
#pragma unroll
                    for (int r = 0; r < 4; ++r)
                        Kt[(size_t)n4 * 1024 + (ct - 4) * 256 + (quad * 4 + r) * 16 + q15] = f2h(vals[r]);
                } else {                            // V tiled, ushort4 (8B) stores
                    ushort4 vv;
                    vv.x = f2h(vals[0]); vv.y = f2h(vals[1]);
                    vv.z = f2h(vals[2]); vv.w = f2h(vals[3]);
                    *(ushort4*)(Vt + (size_t)j32 * 2048 + (ct - 8) * 512 +
                                (h16 * 2 + (quad >> 1)) * 128 + q15 * 8 + (quad & 1) * 4) = vv;
                }
            }
        }
    }
    __threadfence();
    grid.sync();

    // ================= phase 2: attn =================
    const int xcd   = bb & 7;
    const int batch = xcd >> 1;
    const int slot  = (bb >> 3) | ((xcd & 1) << 5);   // 0..63
    const int q0    = slot * 64;
    const size_t base = (size_t)batch * SEQ;

    f16x8 qf[4][2];
#pragma unroll
    for (int g = 0; g < 4; ++g)
#pragma unroll
        for (int h = 0; h < 2; ++h)
            qf[g][h] = *(const f16x8*)(Qw + (base + q0 + g * 16 + q15) * 64 + h * 32 + quad * 8);

    f32x4 oacc[4][4];
#pragma unroll
    for (int g = 0; g < 4; ++g)
#pragma unroll
        for (int dt = 0; dt < 4; ++dt) oacc[g][dt] = (f32x4){0.f, 0.f, 0.f, 0.f};
    float lsum[4] = {0.f, 0.f, 0.f, 0.f};

    const size_t j0g = base + w * 512;
    const ushort* Kfb = Kt + (j0g >> 4) * 1024;
    const ushort* Vfb = Vt + (j0g >> 5) * 2048 + lane * 8;
    short* Ps = aS + w * 5120;                          // 2 bufs x [64 q][40]

    int koff[2][2];
#pragma unroll
    for (int jt = 0; jt < 2; ++jt)
#pragma unroll
        for (int h = 0; h < 2; ++h)
            koff[jt][h] = jt * 1024 + h * 512 + (quad >> 1) * 256 + q15 * 16 + (quad & 1) * 8;

    f16x8 kf[3][2][2], vf[3][4];   // ring-3

#define LOADKV(slotc, i)                                                       \
    {                                                                          \
        _Pragma("unroll") for (int jt = 0; jt < 2; ++jt)                       \
        _Pragma("unroll") for (int h = 0; h < 2; ++h)                          \
            kf[slotc][jt][h] = *(const f16x8*)(Kfb + (size_t)(i) * 2048 + koff[jt][h]); \
        _Pragma("unroll") for (int dt = 0; dt < 4; ++dt)                       \
            vf[slotc][dt] = *(const f16x8*)(Vfb + (size_t)(i) * 2048 + dt * 512); \
    }
#define QKSTEP(slotc, pb)                                                      \
    {                                                                          \
        _Pragma("unroll") for (int g = 0; g < 4; ++g)                          \
        _Pragma("unroll") for (int jt = 0; jt < 2; ++jt) {                     \
            f32x4 z = (f32x4){0.f, 0.f, 0.f, 0.f};                             \
            z = MFMAH(kf[slotc][jt][0], qf[g][0], z);                          \
            z = MFMAH(kf[slotc][jt][1], qf[g][1], z);                          \
            float e0 = exp2f(z.x), e1 = exp2f(z.y);                            \
            float e2 = exp2f(z.z), e3 = exp2f(z.w);                            \
            lsum[g] += (e0 + e1) + (e2 + e3);                                  \
            uint2 pk = make_uint2(pkrtz(e0, e1), pkrtz(e2, e3));               \
            *(uint2*)(Ps + (pb) * 2560 + (g * 16 + q15) * 40 + jt * 16 + quad * 4) = pk; \
        }                                                                      \
    }
#define PVSTEP(slotc, pb)                                                      \
    {                                                                          \
        f16x8 pf[4];                                                           \
        _Pragma("unroll") for (int g = 0; g < 4; ++g)                          \
            pf[g] = *(const f16x8*)(Ps + (pb) * 2560 + (g * 16 + q15) * 40 + quad * 8); \
        __builtin_amdgcn_s_setprio(1);                                         \
        _Pragma("unroll") for (int dt = 0; dt < 4; ++dt)                       \
        _Pragma("unroll") for (int g = 0; g < 4; ++g)                          \
            oacc[g][dt] = MFMAH(pf[g], vf[slotc][dt], oacc[g][dt]);            \
        __builtin_amdgcn_s_setprio(0);                                         \
    }

    LOADKV(0, 0);
    LOADKV(1, 1);
    QKSTEP(0, 0);
#pragma unroll
    for (int i = 0; i < 16; ++i) {
        if (i + 2 < 16) LOADKV((i + 2) % 3, i + 2);
        if (i + 1 < 16) QKSTEP((i + 1) % 3, (i + 1) & 1);
        PVSTEP(i % 3, i & 1);
    }

    // ---- l: quad-reduce, publish per wave ----
#pragma unroll
    for (int g = 0; g < 4; ++g) {
        lsum[g] += __shfl_xor(lsum[g], 16);
        lsum[g] += __shfl_xor(lsum[g], 32);
    }
    if (quad == 0) {
#pragma unroll
        for (int g = 0; g < 4; ++g)
            aF[20480 + w * 64 + g * 16 + q15] = lsum[g];
    }
    __syncthreads();   // P strips dead; l published; combine bufs usable

    // ---- 8-way tree combine of o through LDS (rows padded to OSTR=68) ----
#define OWRITE(idx)                                                          \
    {                                                                        \
        float* b = aF + (idx) * OBUF;                                        \
        _Pragma("unroll") for (int g = 0; g < 4; ++g)                        \
        _Pragma("unroll") for (int dt = 0; dt < 4; ++dt) {                   \
            b[(g * 16 + quad * 4 + 0) * OSTR + dt * 16 + q15] = oacc[g][dt].x; \
            b[(g * 16 + quad * 4 + 1) * OSTR + dt * 16 + q15] = oacc[g][dt].y; \
            b[(g * 16 + quad * 4 + 2) * OSTR + dt * 16 + q15] = oacc[g][dt].z; \
            b[(g * 16 + quad * 4 + 3) * OSTR + dt * 16 + q15] = oacc[g][dt].w; \
        }                                                                    \
    }
#define OADD(idx)                                                            \
    {                                                                        \
        const float* b = aF + (idx) * OBUF;                                  \
        _Pragma("unroll") for (int g = 0; g < 4; ++g)                        \
        _Pragma("unroll") for (int dt = 0; dt < 4; ++dt) {                   \
            oacc[g][dt].x += b[(g * 16 + quad * 4 + 0) * OSTR + dt * 16 + q15];\
            oacc[g][dt].y += b[(g * 16 + quad * 4 + 1) * OSTR + dt * 16 + q15];\
            oacc[g][dt].z += b[(g * 16 + quad * 4 + 2) * OSTR + dt * 16 + q15];\
            oacc[g][dt].w += b[(g * 16 + quad * 4 + 3) * OSTR + dt * 16 + q15];\
        }                                                                    \
    }
    if (w >= 4) OWRITE(w - 4);
    __syncthreads();
    if (w < 4) OADD(w);
    __syncthreads();
    if (w == 2 || w == 3) OWRITE(w - 2);
    __syncthreads();
    if (w < 2) OADD(w);
    __syncthreads();
    if (w < 2) OWRITE(w);
    __syncthreads();

    {
        const int q  = t >> 3;            // 0..63
        const int d0 = (t & 7) * 8;
        float l = 0.f;
#pragma unroll
        for (int i = 0; i < 8; ++i) l += aF[20480 + i * 64 + q];
        const float linv = 1.0f / l;
#pragma unroll
        for (int k2 = 0; k2 < 2; ++k2) {
            float4 a = *(const float4*)&aF[q * OSTR + d0 + k2 * 4];
            float4 b = *(const float4*)&aF[OBUF + q * OSTR + d0 + k2 * 4];
            float4 s;
            s.x = (a.x + b.x) * linv; s.y = (a.y + b.y) * linv;
            s.z = (a.z + b.z) * linv; s.w = (a.w + b.w) * linv;
            *(float4*)(out + (base + q0 + q) * 64 + d0 + k2 * 4) = s;
        }
    }
}

// ---------------------------------------------------------------------------
extern "C" void kernel_launch(void* const* d_in, const int* in_sizes, int n_in,
                              void* d_out, int out_size, void* d_ws, size_t ws_size,
                              hipStream_t stream)
{
    const float* ix = (const float*)d_in[0];
    const float* Wk = (const float*)d_in[1];
    const float* Wq = (const float*)d_in[2];
    const float* Wv = (const float*)d_in[3];
    float* out = (float*)d_out;

    // ws: Qw | Kt | Vt (NROW*64 ushorts each) + WTt (24*192*32 ushorts)
    ushort* Qw  = (ushort*)d_ws;
    ushort* Kt  = Qw + (size_t)NROW * Hm;
    ushort* Vt  = Kt + (size_t)NROW * Hm;
    ushort* WTt = Vt + (size_t)NROW * Hm;

    void* args[] = {(void*)&ix, (void*)&Wq, (void*)&Wk, (void*)&Wv,
                    (void*)&WTt, (void*)&Qw, (void*)&Kt, (void*)&Vt,
                    (void*)&out};
    hipLaunchCooperativeKernel((const void*)fused, dim3(256), dim3(512),
                               args, 0, stream);
}

// Round 4
// 128.949 us; speedup vs baseline: 2.4287x; 2.4287x over previous
//
#include <hip/hip_runtime.h>
#include <math.h>

#define Dm   768
#define Hm   64
#define SEQ  4096
#define NB   4
#define NROW (NB * SEQ)

// scale 1/sqrt(64) and log2(e) folded into Wq at wconv time -> exp2 domain
#define QSCALE (0.125f * 1.4426950408889634f)

typedef _Float16 f16;
typedef __attribute__((ext_vector_type(8))) _Float16 f16x8;
typedef __attribute__((ext_vector_type(2))) __fp16 fp16x2_raw;
typedef __attribute__((ext_vector_type(4))) float f32x4;
typedef unsigned int uint;
typedef unsigned short ushort;

#define MFMAH(A, B, C) __builtin_amdgcn_mfma_f32_16x16x32_f16(A, B, C, 0, 0, 0)

__device__ __forceinline__ uint pkrtz(float a, float b) {
    fp16x2_raw r = __builtin_amdgcn_cvt_pkrtz(a, b);
    return __builtin_bit_cast(uint, r);
}
__device__ __forceinline__ ushort f2h(float f) {
    f16 h = (f16)f;
    return __builtin_bit_cast(ushort, h);
}
union F16x8U { uint u[4]; f16x8 v; };

// ---------------------------------------------------------------------------
// Kernel 0: W -> WTt f16, tiled [kt(24)][c(192)][kk(32)]. c: 0-63 Q (QSCALE
// folded), 64-127 K, 128-191 V. Coalesced: 72 blocks = (kt, mat); read W
// row-major (256B runs/wave), transpose through padded LDS (stride 33,
// <=2-way banks), store WTt contiguous (128B runs/wave). Replaces the old
// stride-256B column reads (16x line overfetch, latency-serial).
// ---------------------------------------------------------------------------
__global__ __launch_bounds__(256) void wconv(
    const float* __restrict__ Wq, const float* __restrict__ Wk,
    const float* __restrict__ Wv, ushort* __restrict__ WTt)
{
    __shared__ ushort lt[64 * 33];
    const int b  = blockIdx.x;            // 72 = 24 kt x 3 mat
    const int kt = b / 3, m = b - kt * 3;
    const float* W = (m == 0) ? Wq : (m == 1 ? Wk : Wv);
    const float sc = (m == 0) ? QSCALE : 1.0f;
    const int t = threadIdx.x;
#pragma unroll
    for (int p = 0; p < 8; ++p) {
        int t2 = p * 256 + t;
        int kl = t2 >> 6, c = t2 & 63;
        lt[c * 33 + kl] = f2h(W[(size_t)(kt * 32 + kl) * 64 + c] * sc);
    }
    __syncthreads();
#pragma unroll
    for (int p = 0; p < 8; ++p) {
        int t2 = p * 256 + t;
        int c = t2 >> 5, kk = t2 & 31;
        WTt[((size_t)kt * 192 + m * 64 + c) * 32 + kk] = lt[c * 33 + kk];
    }
}

// ---------------------------------------------------------------------------
// Kernel 1: f16 MFMA QKV projection, split-K=4, 32 rows/block (512 blocks).
// Each wave kh owns K range [kh*192, +192) = 6 iters of 32, and processes
// TWO 16-row tiles with the SAME Bf[12] set -> B-fragment L2 traffic halves
// vs 16-row blocks (301MB -> 150MB). acc[2][12] = 96 VGPR, est ~220 live:
// LB(256,2) caps at 256 VGPR (the 170 cap of LB(256,3) spilled historically).
// 2 blocks/CU (48KB LDS x2 = 96KB), 8 waves/CU. A: ix fp32 ring-3
// distance-2 register prefetch per tile. 4-way tree combine, kh==0 stores.
// ---------------------------------------------------------------------------
__global__ __launch_bounds__(256, 2) void proj(
    const float* __restrict__ ix, const ushort* __restrict__ WTt,
    ushort* __restrict__ Qw, ushort* __restrict__ Kt, ushort* __restrict__ Vt)
{
    __shared__ __align__(16) float comb[2][2][3072];   // 48 KiB

    const int t    = threadIdx.x;
    const int lane = t & 63;
    const int kh   = __builtin_amdgcn_readfirstlane(t >> 6);  // split-K index
    const int q15  = lane & 15, quad = lane >> 4;
    const int gr0  = blockIdx.x * 32;

    const float* Ab0 = ix + (size_t)(gr0 + q15) * Dm + kh * 192 + quad * 8;
    const float* Ab1 = Ab0 + (size_t)16 * Dm;
    const ushort* Bb = WTt + ((size_t)(kh * 6) * 192 + q15) * 32 + quad * 8;

    f32x4 acc[2][12];
#pragma unroll
    for (int rt = 0; rt < 2; ++rt)
#pragma unroll
        for (int ct = 0; ct < 12; ++ct) acc[rt][ct] = (f32x4){0.f, 0.f, 0.f, 0.f};

    f32x4 Af[2][3][2];   // [tile][ring-3][half], distance-2
#pragma unroll
    for (int i = 0; i < 2; ++i) {
        Af[0][i][0] = *(const f32x4*)(Ab0 + i * 32);
        Af[0][i][1] = *(const f32x4*)(Ab0 + i * 32 + 4);
        Af[1][i][0] = *(const f32x4*)(Ab1 + i * 32);
        Af[1][i][1] = *(const f32x4*)(Ab1 + i * 32 + 4);
    }

#pragma unroll
    for (int it = 0; it < 6; ++it) {
        // B loads first (L2-hot, single buffer, one live set, reused 2x)
        f16x8 Bf[12];
#pragma unroll
        for (int ct = 0; ct < 12; ++ct)
            Bf[ct] = *(const f16x8*)(Bb + (size_t)it * 6144 + ct * 512);

        if (it + 2 < 6) {
            Af[0][(it + 2) % 3][0] = *(const f32x4*)(Ab0 + (it + 2) * 32);
            Af[0][(it + 2) % 3][1] = *(const f32x4*)(Ab0 + (it + 2) * 32 + 4);
            Af[1][(it + 2) % 3][0] = *(const f32x4*)(Ab1 + (it + 2) * 32);
            Af[1][(it + 2) % 3][1] = *(const f32x4*)(Ab1 + (it + 2) * 32 + 4);
        }

        F16x8U af0, af1;
        af0.u[0] = pkrtz(Af[0][it % 3][0].x, Af[0][it % 3][0].y);
        af0.u[1] = pkrtz(Af[0][it % 3][0].z, Af[0][it % 3][0].w);
        af0.u[2] = pkrtz(Af[0][it % 3][1].x, Af[0][it % 3][1].y);
        af0.u[3] = pkrtz(Af[0][it % 3][1].z, Af[0][it % 3][1].w);
        af1.u[0] = pkrtz(Af[1][it % 3][0].x, Af[1][it % 3][0].y);
        af1.u[1] = pkrtz(Af[1][it % 3][0].z, Af[1][it % 3][0].w);
        af1.u[2] = pkrtz(Af[1][it % 3][1].x, Af[1][it % 3][1].y);
        af1.u[3] = pkrtz(Af[1][it % 3][1].z, Af[1][it % 3][1].w);
        __builtin_amdgcn_s_setprio(1);
#pragma unroll
        for (int ct = 0; ct < 12; ++ct) {
            acc[0][ct] = MFMAH(af0.v, Bf[ct], acc[0][ct]);
            acc[1][ct] = MFMAH(af1.v, Bf[ct], acc[1][ct]);
        }
        __builtin_amdgcn_s_setprio(0);
    }

    // ---- 4-way split-K combine: (0+=2, 1+=3), 1 writes, 0 += ----
    if (kh >= 2) {
#pragma unroll
        for (int rt = 0; rt < 2; ++rt)
#pragma unroll
            for (int ct = 0; ct < 12; ++ct)
                *(f32x4*)&comb[rt][kh - 2][(ct * 64 + lane) * 4] = acc[rt][ct];
    }
    __syncthreads();
    if (kh < 2) {
#pragma unroll
        for (int rt = 0; rt < 2; ++rt)
#pragma unroll
            for (int ct = 0; ct < 12; ++ct) {
                f32x4 o = *(const f32x4*)&comb[rt][kh][(ct * 64 + lane) * 4];
                acc[rt][ct].x += o.x; acc[rt][ct].y += o.y;
                acc[rt][ct].z += o.z; acc[rt][ct].w += o.w;
            }
    }
    __syncthreads();
    if (kh == 1) {
#pragma unroll
        for (int rt = 0; rt < 2; ++rt)
#pragma unroll
            for (int ct = 0; ct < 12; ++ct)
                *(f32x4*)&comb[rt][0][(ct * 64 + lane) * 4] = acc[rt][ct];
    }
    __syncthreads();
    if (kh == 0) {
#pragma unroll
        for (int rt = 0; rt < 2; ++rt) {
#pragma unroll
            for (int ct = 0; ct < 12; ++ct) {
                f32x4 o = *(const f32x4*)&comb[rt][0][(ct * 64 + lane) * 4];
                acc[rt][ct].x += o.x; acc[rt][ct].y += o.y;
                acc[rt][ct].z += o.z; acc[rt][ct].w += o.w;
            }
            const int gr  = gr0 + rt * 16;
            const int n4  = gr >> 4;
            const int h16 = n4 & 1;
            const int j32 = gr >> 5;
#pragma unroll
            for (int ct = 0; ct < 12; ++ct) {
                float vals[4] = {acc[rt][ct].x, acc[rt][ct].y, acc[rt][ct].z, acc[rt][ct].w};
                if (ct < 4) {                       // Q: row-major, 32B runs
#pragma unroll
                    for (int r = 0; r < 4; ++r)
                        Qw[(size_t)(gr + quad * 4 + r) * 64 + ct * 16 + q15] = f2h(vals[r]);
                } else if (ct < 8) {                // K tiled: [j>>4][k>>4][j&15][k&15]
#pragma unroll
                    for (int r = 0; r < 4; ++r)
                        Kt[(size_t)n4 * 1024 + (ct - 4) * 256 + (quad * 4 + r) * 16 + q15] = f2h(vals[r]);
                } else {                            // V tiled, ushort4 (8B) stores
                    ushort4 vv;
                    vv.x = f2h(vals[0]); vv.y = f2h(vals[1]);
                    vv.z = f2h(vals[2]); vv.w = f2h(vals[3]);
                    *(ushort4*)(Vt + (size_t)j32 * 2048 + (ct - 8) * 512 +
                                (h16 * 2 + (quad >> 1)) * 128 + q15 * 8 + (quad & 1) * 4) = vv;
                }
            }
        }
    }
}

// ---------------------------------------------------------------------------
// Kernel 2: f16 MFMA flash attention, software-pipelined. grid 256 x 512.
// Block = 64 queries; wave w owns j in [w*512, +512) = 16 iters of 32 keys.
// K/V fragments: distance-2 ring-3 register prefetch from global (1KB
// contiguous per instr). PV lags QK by ONE iteration with double-buffered
// P strips -> the LDS P round-trip gets a full iteration of latency cover.
// Loop fully unrolled (ring indices constant). No-max exp2 softmax.
// s_setprio(1) around the PV 16-MFMA cluster. Combine rows padded to 68
// floats (2-way banks). This is the round-1 measured-baseline attn verbatim.
// ---------------------------------------------------------------------------
#define OSTR 68
#define OBUF 4352   // 64 rows * 68 floats per combine buffer

__global__ __launch_bounds__(512, 2) void attn(
    const ushort* __restrict__ Qw, const ushort* __restrict__ Kt,
    const ushort* __restrict__ Vt, float* __restrict__ out)
{
    // floats [0,17408): combine bufs (4 x 4352), aliased by P strips during
    // the loop (shorts [0, 8*5120)). floats [20480,20992): l per wave.
    __shared__ __align__(16) float aF[20992];   // 83968 B
    short* aS = (short*)aF;

    const int t    = threadIdx.x;
    const int lane = t & 63;
    const int w    = __builtin_amdgcn_readfirstlane(t >> 6);
    const int q15  = lane & 15, quad = lane >> 4;

    const int bb    = blockIdx.x;
    const int xcd   = bb & 7;
    const int batch = xcd >> 1;
    const int slot  = (bb >> 3) | ((xcd & 1) << 5);   // 0..63
    const int q0    = slot * 64;
    const size_t base = (size_t)batch * SEQ;

    f16x8 qf[4][2];
#pragma unroll
    for (int g = 0; g < 4; ++g)
#pragma unroll
        for (int h = 0; h < 2; ++h)
            qf[g][h] = *(const f16x8*)(Qw + (base + q0 + g * 16 + q15) * 64 + h * 32 + quad * 8);

    f32x4 oacc[4][4];
#pragma unroll
    for (int g = 0; g < 4; ++g)
#pragma unroll
        for (int dt = 0; dt < 4; ++dt) oacc[g][dt] = (f32x4){0.f, 0.f, 0.f, 0.f};
    float lsum[4] = {0.f, 0.f, 0.f, 0.f};

    const size_t j0g = base + w * 512;
    const ushort* Kfb = Kt + (j0g >> 4) * 1024;
    const ushort* Vfb = Vt + (j0g >> 5) * 2048 + lane * 8;
    short* Ps = aS + w * 5120;                          // 2 bufs x [64 q][40]

    int koff[2][2];
#pragma unroll
    for (int jt = 0; jt < 2; ++jt)
#pragma unroll
        for (int h = 0; h < 2; ++h)
            koff[jt][h] = jt * 1024 + h * 512 + (quad >> 1) * 256 + q15 * 16 + (quad & 1) * 8;

    f16x8 kf[3][2][2], vf[3][4];   // ring-3

#define LOADKV(slotc, i)                                                       \
    {                                                                          \
        _Pragma("unroll") for (int jt = 0; jt < 2; ++jt)                       \
        _Pragma("unroll") for (int h = 0; h < 2; ++h)                          \
            kf[slotc][jt][h] = *(const f16x8*)(Kfb + (size_t)(i) * 2048 + koff[jt][h]); \
        _Pragma("unroll") for (int dt = 0; dt < 4; ++dt)                       \
            vf[slotc][dt] = *(const f16x8*)(Vfb + (size_t)(i) * 2048 + dt * 512); \
    }
#define QKSTEP(slotc, pb)                                                      \
    {                                                                          \
        _Pragma("unroll") for (int g = 0; g < 4; ++g)                          \
        _Pragma("unroll") for (int jt = 0; jt < 2; ++jt) {                     \
            f32x4 z = (f32x4){0.f, 0.f, 0.f, 0.f};                             \
            z = MFMAH(kf[slotc][jt][0], qf[g][0], z);                          \
            z = MFMAH(kf[slotc][jt][1], qf[g][1], z);                          \
            float e0 = exp2f(z.x), e1 = exp2f(z.y);                            \
            float e2 = exp2f(z.z), e3 = exp2f(z.w);                            \
            lsum[g] += (e0 + e1) + (e2 + e3);                                  \
            uint2 pk = make_uint2(pkrtz(e0, e1), pkrtz(e2, e3));               \
            *(uint2*)(Ps + (pb) * 2560 + (g * 16 + q15) * 40 + jt * 16 + quad * 4) = pk; \
        }                                                                      \
    }
#define PVSTEP(slotc, pb)                                                      \
    {                                                                          \
        f16x8 pf[4];                                                           \
        _Pragma("unroll") for (int g = 0; g < 4; ++g)                          \
            pf[g] = *(const f16x8*)(Ps + (pb) * 2560 + (g * 16 + q15) * 40 + quad * 8); \
        __builtin_amdgcn_s_setprio(1);                                         \
        _Pragma("unroll") for (int dt = 0; dt < 4; ++dt)                       \
        _Pragma("unroll") for (int g = 0; g < 4; ++g)                          \
            oacc[g][dt] = MFMAH(pf[g], vf[slotc][dt], oacc[g][dt]);            \
        __builtin_amdgcn_s_setprio(0);                                         \
    }

    LOADKV(0, 0);
    LOADKV(1, 1);
    QKSTEP(0, 0);
#pragma unroll
    for (int i = 0; i < 16; ++i) {
        if (i + 2 < 16) LOADKV((i + 2) % 3, i + 2);
        if (i + 1 < 16) QKSTEP((i + 1) % 3, (i + 1) & 1);
        PVSTEP(i % 3, i & 1);
    }

    // ---- l: quad-reduce, publish per wave ----
#pragma unroll
    for (int g = 0; g < 4; ++g) {
        lsum[g] += __shfl_xor(lsum[g], 16);
        lsum[g] += __shfl_xor(lsum[g], 32);
    }
    if (quad == 0) {
#pragma unroll
        for (int g = 0; g < 4; ++g)
            aF[20480 + w * 64 + g * 16 + q15] = lsum[g];
    }
    __syncthreads();   // P strips dead; l published; combine bufs usable

    // ---- 8-way tree combine of o through LDS (rows padded to OSTR=68) ----
#define OWRITE(idx)                                                          \
    {                                                                        \
        float* b = aF + (idx) * OBUF;                                        \
        _Pragma("unroll") for (int g = 0; g < 4; ++g)                        \
        _Pragma("unroll") for (int dt = 0; dt < 4; ++dt) {                   \
            b[(g * 16 + quad * 4 + 0) * OSTR + dt * 16 + q15] = oacc[g][dt].x; \
            b[(g * 16 + quad * 4 + 1) * OSTR + dt * 16 + q15] = oacc[g][dt].y; \
            b[(g * 16 + quad * 4 + 2) * OSTR + dt * 16 + q15] = oacc[g][dt].z; \
            b[(g * 16 + quad * 4 + 3) * OSTR + dt * 16 + q15] = oacc[g][dt].w; \
        }                                                                    \
    }
#define OADD(idx)                                                            \
    {                                                                        \
        const float* b = aF + (idx) * OBUF;                                  \
        _Pragma("unroll") for (int g = 0; g < 4; ++g)                        \
        _Pragma("unroll") for (int dt = 0; dt < 4; ++dt) {                   \
            oacc[g][dt].x += b[(g * 16 + quad * 4 + 0) * OSTR + dt * 16 + q15];\
            oacc[g][dt].y += b[(g * 16 + quad * 4 + 1) * OSTR + dt * 16 + q15];\
            oacc[g][dt].z += b[(g * 16 + quad * 4 + 2) * OSTR + dt * 16 + q15];\
            oacc[g][dt].w += b[(g * 16 + quad * 4 + 3) * OSTR + dt * 16 + q15];\
        }                                                                    \
    }
    if (w >= 4) OWRITE(w - 4);
    __syncthreads();
    if (w < 4) OADD(w);
    __syncthreads();
    if (w == 2 || w == 3) OWRITE(w - 2);
    __syncthreads();
    if (w < 2) OADD(w);
    __syncthreads();
    if (w < 2) OWRITE(w);
    __syncthreads();

    {
        const int q  = t >> 3;            // 0..63
        const int d0 = (t & 7) * 8;
        float l = 0.f;
#pragma unroll
        for (int i = 0; i < 8; ++i) l += aF[20480 + i * 64 + q];
        const float linv = 1.0f / l;
#pragma unroll
        for (int k2 = 0; k2 < 2; ++k2) {
            float4 a = *(const float4*)&aF[q * OSTR + d0 + k2 * 4];
            float4 b = *(const float4*)&aF[OBUF + q * OSTR + d0 + k2 * 4];
            float4 s;
            s.x = (a.x + b.x) * linv; s.y = (a.y + b.y) * linv;
            s.z = (a.z + b.z) * linv; s.w = (a.w + b.w) * linv;
            *(float4*)(out + (base + q0 + q) * 64 + d0 + k2 * 4) = s;
        }
    }
}

// ---------------------------------------------------------------------------
extern "C" void kernel_launch(void* const* d_in, const int* in_sizes, int n_in,
                              void* d_out, int out_size, void* d_ws, size_t ws_size,
                              hipStream_t stream)
{
    const float* ix = (const float*)d_in[0];
    const float* Wk = (const float*)d_in[1];
    const float* Wq = (const float*)d_in[2];
    const float* Wv = (const float*)d_in[3];
    float* out = (float*)d_out;

    // ws: Qw | Kt | Vt (NROW*64 ushorts each) + WTt (24*192*32 ushorts)
    ushort* Qw  = (ushort*)d_ws;
    ushort* Kt  = Qw + (size_t)NROW * Hm;
    ushort* Vt  = Kt + (size_t)NROW * Hm;
    ushort* WTt = Vt + (size_t)NROW * Hm;

    wconv<<<72, 256, 0, stream>>>(Wq, Wk, Wv, WTt);
    proj<<<512, 256, 0, stream>>>(ix, WTt, Qw, Kt, Vt);
    attn<<<256, 512, 0, stream>>>(Qw, Kt, Vt, out);
}

// Round 5
// 127.967 us; speedup vs baseline: 2.4473x; 1.0077x over previous
//
#include <hip/hip_runtime.h>
#include <math.h>

#define Dm   768
#define Hm   64
#define SEQ  4096
#define NB   4
#define NROW (NB * SEQ)

// scale 1/sqrt(64) and log2(e) folded into Wq at wconv time -> exp2 domain
#define QSCALE (0.125f * 1.4426950408889634f)

typedef _Float16 f16;
typedef __attribute__((ext_vector_type(8))) _Float16 f16x8;
typedef __attribute__((ext_vector_type(2))) __fp16 fp16x2_raw;
typedef __attribute__((ext_vector_type(4))) float f32x4;
typedef unsigned int uint;
typedef unsigned short ushort;

#define MFMAH(A, B, C) __builtin_amdgcn_mfma_f32_16x16x32_f16(A, B, C, 0, 0, 0)

__device__ __forceinline__ uint pkrtz(float a, float b) {
    fp16x2_raw r = __builtin_amdgcn_cvt_pkrtz(a, b);
    return __builtin_bit_cast(uint, r);
}
__device__ __forceinline__ ushort f2h(float f) {
    f16 h = (f16)f;
    return __builtin_bit_cast(ushort, h);
}
union F16x8U { uint u[4]; f16x8 v; };

// ---------------------------------------------------------------------------
// Kernel 0: W -> WTt f16, tiled [kt(24)][c(192)][kk(32)]. c: 0-63 Q (QSCALE
// folded), 64-127 K, 128-191 V. Coalesced: 72 blocks = (kt, mat); read W
// row-major (256B runs/wave), transpose through padded LDS (stride 33,
// <=2-way banks), store WTt contiguous (128B runs/wave).
// ---------------------------------------------------------------------------
__global__ __launch_bounds__(256) void wconv(
    const float* __restrict__ Wq, const float* __restrict__ Wk,
    const float* __restrict__ Wv, ushort* __restrict__ WTt)
{
    __shared__ ushort lt[64 * 33];
    const int b  = blockIdx.x;            // 72 = 24 kt x 3 mat
    const int kt = b / 3, m = b - kt * 3;
    const float* W = (m == 0) ? Wq : (m == 1 ? Wk : Wv);
    const float sc = (m == 0) ? QSCALE : 1.0f;
    const int t = threadIdx.x;
#pragma unroll
    for (int p = 0; p < 8; ++p) {
        int t2 = p * 256 + t;
        int kl = t2 >> 6, c = t2 & 63;
        lt[c * 33 + kl] = f2h(W[(size_t)(kt * 32 + kl) * 64 + c] * sc);
    }
    __syncthreads();
#pragma unroll
    for (int p = 0; p < 8; ++p) {
        int t2 = p * 256 + t;
        int c = t2 >> 5, kk = t2 & 31;
        WTt[((size_t)kt * 192 + m * 64 + c) * 32 + kk] = lt[c * 33 + kk];
    }
}

// ---------------------------------------------------------------------------
// Kernel 1: f16 MFMA QKV projection, split-K=4, 32 rows/block (512 blocks).
// Each wave kh owns K range [kh*192, +192) = 6 iters of 32, and processes
// TWO 16-row tiles with the SAME Bf[12] set -> B-fragment L2 traffic halves
// vs 16-row blocks (301MB -> 150MB). LB(256,2), 2 blocks/CU (48KB LDS x2).
// A: ix fp32 ring-3 distance-2 register prefetch per tile. 4-way tree
// combine, kh==0 stores. (Measured good in R4 — unchanged.)
// ---------------------------------------------------------------------------
__global__ __launch_bounds__(256, 2) void proj(
    const float* __restrict__ ix, const ushort* __restrict__ WTt,
    ushort* __restrict__ Qw, ushort* __restrict__ Kt, ushort* __restrict__ Vt)
{
    __shared__ __align__(16) float comb[2][2][3072];   // 48 KiB

    const int t    = threadIdx.x;
    const int lane = t & 63;
    const int kh   = __builtin_amdgcn_readfirstlane(t >> 6);  // split-K index
    const int q15  = lane & 15, quad = lane >> 4;
    const int gr0  = blockIdx.x * 32;

    const float* Ab0 = ix + (size_t)(gr0 + q15) * Dm + kh * 192 + quad * 8;
    const float* Ab1 = Ab0 + (size_t)16 * Dm;
    const ushort* Bb = WTt + ((size_t)(kh * 6) * 192 + q15) * 32 + quad * 8;

    f32x4 acc[2][12];
#pragma unroll
    for (int rt = 0; rt < 2; ++rt)
#pragma unroll
        for (int ct = 0; ct < 12; ++ct) acc[rt][ct] = (f32x4){0.f, 0.f, 0.f, 0.f};

    f32x4 Af[2][3][2];   // [tile][ring-3][half], distance-2
#pragma unroll
    for (int i = 0; i < 2; ++i) {
        Af[0][i][0] = *(const f32x4*)(Ab0 + i * 32);
        Af[0][i][1] = *(const f32x4*)(Ab0 + i * 32 + 4);
        Af[1][i][0] = *(const f32x4*)(Ab1 + i * 32);
        Af[1][i][1] = *(const f32x4*)(Ab1 + i * 32 + 4);
    }

#pragma unroll
    for (int it = 0; it < 6; ++it) {
        // B loads first (L2-hot, single buffer, one live set, reused 2x)
        f16x8 Bf[12];
#pragma unroll
        for (int ct = 0; ct < 12; ++ct)
            Bf[ct] = *(const f16x8*)(Bb + (size_t)it * 6144 + ct * 512);

        if (it + 2 < 6) {
            Af[0][(it + 2) % 3][0] = *(const f32x4*)(Ab0 + (it + 2) * 32);
            Af[0][(it + 2) % 3][1] = *(const f32x4*)(Ab0 + (it + 2) * 32 + 4);
            Af[1][(it + 2) % 3][0] = *(const f32x4*)(Ab1 + (it + 2) * 32);
            Af[1][(it + 2) % 3][1] = *(const f32x4*)(Ab1 + (it + 2) * 32 + 4);
        }

        F16x8U af0, af1;
        af0.u[0] = pkrtz(Af[0][it % 3][0].x, Af[0][it % 3][0].y);
        af0.u[1] = pkrtz(Af[0][it % 3][0].z, Af[0][it % 3][0].w);
        af0.u[2] = pkrtz(Af[0][it % 3][1].x, Af[0][it % 3][1].y);
        af0.u[3] = pkrtz(Af[0][it % 3][1].z, Af[0][it % 3][1].w);
        af1.u[0] = pkrtz(Af[1][it % 3][0].x, Af[1][it % 3][0].y);
        af1.u[1] = pkrtz(Af[1][it % 3][0].z, Af[1][it % 3][0].w);
        af1.u[2] = pkrtz(Af[1][it % 3][1].x, Af[1][it % 3][1].y);
        af1.u[3] = pkrtz(Af[1][it % 3][1].z, Af[1][it % 3][1].w);
        __builtin_amdgcn_s_setprio(1);
#pragma unroll
        for (int ct = 0; ct < 12; ++ct) {
            acc[0][ct] = MFMAH(af0.v, Bf[ct], acc[0][ct]);
            acc[1][ct] = MFMAH(af1.v, Bf[ct], acc[1][ct]);
        }
        __builtin_amdgcn_s_setprio(0);
    }

    // ---- 4-way split-K combine: (0+=2, 1+=3), 1 writes, 0 += ----
    if (kh >= 2) {
#pragma unroll
        for (int rt = 0; rt < 2; ++rt)
#pragma unroll
            for (int ct = 0; ct < 12; ++ct)
                *(f32x4*)&comb[rt][kh - 2][(ct * 64 + lane) * 4] = acc[rt][ct];
    }
    __syncthreads();
    if (kh < 2) {
#pragma unroll
        for (int rt = 0; rt < 2; ++rt)
#pragma unroll
            for (int ct = 0; ct < 12; ++ct) {
                f32x4 o = *(const f32x4*)&comb[rt][kh][(ct * 64 + lane) * 4];
                acc[rt][ct].x += o.x; acc[rt][ct].y += o.y;
                acc[rt][ct].z += o.z; acc[rt][ct].w += o.w;
            }
    }
    __syncthreads();
    if (kh == 1) {
#pragma unroll
        for (int rt = 0; rt < 2; ++rt)
#pragma unroll
            for (int ct = 0; ct < 12; ++ct)
                *(f32x4*)&comb[rt][0][(ct * 64 + lane) * 4] = acc[rt][ct];
    }
    __syncthreads();
    if (kh == 0) {
#pragma unroll
        for (int rt = 0; rt < 2; ++rt) {
#pragma unroll
            for (int ct = 0; ct < 12; ++ct) {
                f32x4 o = *(const f32x4*)&comb[rt][0][(ct * 64 + lane) * 4];
                acc[rt][ct].x += o.x; acc[rt][ct].y += o.y;
                acc[rt][ct].z += o.z; acc[rt][ct].w += o.w;
            }
            const int gr  = gr0 + rt * 16;
            const int n4  = gr >> 4;
            const int h16 = n4 & 1;
            const int j32 = gr >> 5;
#pragma unroll
            for (int ct = 0; ct < 12; ++ct) {
                float vals[4] = {acc[rt][ct].x, acc[rt][ct].y, acc[rt][ct].z, acc[rt][ct].w};
                if (ct < 4) {                       // Q: row-major, 32B runs
#pragma unroll
                    for (int r = 0; r < 4; ++r)
                        Qw[(size_t)(gr + quad * 4 + r) * 64 + ct * 16 + q15] = f2h(vals[r]);
                } else if (ct < 8) {                // K tiled: [j>>4][k>>4][j&15][k&15]
#pragma unroll
                    for (int r = 0; r < 4; ++r)
                        Kt[(size_t)n4 * 1024 + (ct - 4) * 256 + (quad * 4 + r) * 16 + q15] = f2h(vals[r]);
                } else {                            // V tiled, ushort4 (8B) stores
                    ushort4 vv;
                    vv.x = f2h(vals[0]); vv.y = f2h(vals[1]);
                    vv.z = f2h(vals[2]); vv.w = f2h(vals[3]);
                    *(ushort4*)(Vt + (size_t)j32 * 2048 + (ct - 8) * 512 +
                                (h16 * 2 + (quad >> 1)) * 128 + q15 * 8 + (quad & 1) * 4) = vv;
                }
            }
        }
    }
}

// ---------------------------------------------------------------------------
// Kernel 2: f16 MFMA flash attention. grid 256 x 512. Block = 64 queries;
// wave w owns j in [w*512, +512) = 16 iters of 32 keys.
// RESTRUCTURED PIPELINE (this round): per body, MFMAs are clustered --
//   PFLOAD (ds_read pf, early) ; setprio(1) ; QK-MFMA(i+1) -> z regs ;
//   PV-MFMA(i) ; setprio(0) ; LOADKV(i+2) ; SMPACK(i+1) (exp2+pack+P-write).
// Previously the 32-exp2 TRANS wall sat BETWEEN the QK and PV MFMA clusters
// in issue order (in-order wave issue, 2 waves/SIMD); now softmax of tile
// i+1 executes in the MFMA shadow. z (8 x f32x4 = 32 VGPR) is paid for by
// cutting the K/V ring 3 -> 2 (-32 VGPR): kf(i+2) loaded body i, consumed
// body i+1 (~SMPACK-length later, covers L2 ~200cy); vf consumed 2 bodies
// later. Net VGPR 0. Numerics, P double-buffering, LDS unchanged.
// ---------------------------------------------------------------------------
#define OSTR 68
#define OBUF 4352   // 64 rows * 68 floats per combine buffer

__global__ __launch_bounds__(512, 2) void attn(
    const ushort* __restrict__ Qw, const ushort* __restrict__ Kt,
    const ushort* __restrict__ Vt, float* __restrict__ out)
{
    // floats [0,17408): combine bufs (4 x 4352), aliased by P strips during
    // the loop (shorts [0, 8*5120)). floats [20480,20992): l per wave.
    __shared__ __align__(16) float aF[20992];   // 83968 B
    short* aS = (short*)aF;

    const int t    = threadIdx.x;
    const int lane = t & 63;
    const int w    = __builtin_amdgcn_readfirstlane(t >> 6);
    const int q15  = lane & 15, quad = lane >> 4;

    const int bb    = blockIdx.x;
    const int xcd   = bb & 7;
    const int batch = xcd >> 1;
    const int slot  = (bb >> 3) | ((xcd & 1) << 5);   // 0..63
    const int q0    = slot * 64;
    const size_t base = (size_t)batch * SEQ;

    f16x8 qf[4][2];
#pragma unroll
    for (int g = 0; g < 4; ++g)
#pragma unroll
        for (int h = 0; h < 2; ++h)
            qf[g][h] = *(const f16x8*)(Qw + (base + q0 + g * 16 + q15) * 64 + h * 32 + quad * 8);

    f32x4 oacc[4][4];
#pragma unroll
    for (int g = 0; g < 4; ++g)
#pragma unroll
        for (int dt = 0; dt < 4; ++dt) oacc[g][dt] = (f32x4){0.f, 0.f, 0.f, 0.f};
    float lsum[4] = {0.f, 0.f, 0.f, 0.f};

    const size_t j0g = base + w * 512;
    const ushort* Kfb = Kt + (j0g >> 4) * 1024;
    const ushort* Vfb = Vt + (j0g >> 5) * 2048 + lane * 8;
    short* Ps = aS + w * 5120;                          // 2 bufs x [64 q][40]

    int koff[2][2];
#pragma unroll
    for (int jt = 0; jt < 2; ++jt)
#pragma unroll
        for (int h = 0; h < 2; ++h)
            koff[jt][h] = jt * 1024 + h * 512 + (quad >> 1) * 256 + q15 * 16 + (quad & 1) * 8;

    f16x8 kf[2][2][2], vf[2][4];   // ring-2
    f32x4 zz[4][2];                // deferred QK results (tile i+1)
    f16x8 pf[4];

#define LOADKV(slotc, i)                                                       \
    {                                                                          \
        _Pragma("unroll") for (int jt = 0; jt < 2; ++jt)                       \
        _Pragma("unroll") for (int h = 0; h < 2; ++h)                          \
            kf[slotc][jt][h] = *(const f16x8*)(Kfb + (size_t)(i) * 2048 + koff[jt][h]); \
        _Pragma("unroll") for (int dt = 0; dt < 4; ++dt)                       \
            vf[slotc][dt] = *(const f16x8*)(Vfb + (size_t)(i) * 2048 + dt * 512); \
    }
#define QKMM(slotc)                                                            \
    {                                                                          \
        _Pragma("unroll") for (int g = 0; g < 4; ++g)                          \
        _Pragma("unroll") for (int jt = 0; jt < 2; ++jt) {                     \
            f32x4 z = (f32x4){0.f, 0.f, 0.f, 0.f};                             \
            z = MFMAH(kf[slotc][jt][0], qf[g][0], z);                          \
            z = MFMAH(kf[slotc][jt][1], qf[g][1], z);                          \
            zz[g][jt] = z;                                                     \
        }                                                                      \
    }
#define SMPACK(pb)                                                             \
    {                                                                          \
        _Pragma("unroll") for (int g = 0; g < 4; ++g)                          \
        _Pragma("unroll") for (int jt = 0; jt < 2; ++jt) {                     \
            float e0 = exp2f(zz[g][jt].x), e1 = exp2f(zz[g][jt].y);            \
            float e2 = exp2f(zz[g][jt].z), e3 = exp2f(zz[g][jt].w);            \
            lsum[g] += (e0 + e1) + (e2 + e3);                                  \
            uint2 pk = make_uint2(pkrtz(e0, e1), pkrtz(e2, e3));               \
            *(uint2*)(Ps + (pb) * 2560 + (g * 16 + q15) * 40 + jt * 16 + quad * 4) = pk; \
        }                                                                      \
    }
#define PFLOAD(pb)                                                             \
    {                                                                          \
        _Pragma("unroll") for (int g = 0; g < 4; ++g)                          \
            pf[g] = *(const f16x8*)(Ps + (pb) * 2560 + (g * 16 + q15) * 40 + quad * 8); \
    }
#define PVMM(slotc)                                                            \
    {                                                                          \
        _Pragma("unroll") for (int dt = 0; dt < 4; ++dt)                       \
        _Pragma("unroll") for (int g = 0; g < 4; ++g)                          \
            oacc[g][dt] = MFMAH(pf[g], vf[slotc][dt], oacc[g][dt]);            \
    }

    LOADKV(0, 0);
    LOADKV(1, 1);
    QKMM(0);
    SMPACK(0);
#pragma unroll
    for (int i = 0; i < 16; ++i) {
        PFLOAD(i & 1);                       // early ds_read, used in PVMM
        __builtin_amdgcn_s_setprio(1);
        if (i + 1 < 16) QKMM((i + 1) & 1);   // 16 MFMA -> zz (kept in regs)
        PVMM(i & 1);                         // 16 MFMA, tile i
        __builtin_amdgcn_s_setprio(0);
        if (i + 2 < 16) LOADKV(i & 1, i + 2);// ring-2 slot just freed
        if (i + 1 < 16) SMPACK((i + 1) & 1); // softmax in next-body MFMA shadow
    }

    // ---- l: quad-reduce, publish per wave ----
#pragma unroll
    for (int g = 0; g < 4; ++g) {
        lsum[g] += __shfl_xor(lsum[g], 16);
        lsum[g] += __shfl_xor(lsum[g], 32);
    }
    if (quad == 0) {
#pragma unroll
        for (int g = 0; g < 4; ++g)
            aF[20480 + w * 64 + g * 16 + q15] = lsum[g];
    }
    __syncthreads();   // P strips dead; l published; combine bufs usable

    // ---- 8-way tree combine of o through LDS (rows padded to OSTR=68) ----
#define OWRITE(idx)                                                          \
    {                                                                        \
        float* b = aF + (idx) * OBUF;                                        \
        _Pragma("unroll") for (int g = 0; g < 4; ++g)                        \
        _Pragma("unroll") for (int dt = 0; dt < 4; ++dt) {                   \
            b[(g * 16 + quad * 4 + 0) * OSTR + dt * 16 + q15] = oacc[g][dt].x; \
            b[(g * 16 + quad * 4 + 1) * OSTR + dt * 16 + q15] = oacc[g][dt].y; \
            b[(g * 16 + quad * 4 + 2) * OSTR + dt * 16 + q15] = oacc[g][dt].z; \
            b[(g * 16 + quad * 4 + 3) * OSTR + dt * 16 + q15] = oacc[g][dt].w; \
        }                                                                    \
    }
#define OADD(idx)                                                            \
    {                                                                        \
        const float* b = aF + (idx) * OBUF;                                  \
        _Pragma("unroll") for (int g = 0; g < 4; ++g)                        \
        _Pragma("unroll") for (int dt = 0; dt < 4; ++dt) {                   \
            oacc[g][dt].x += b[(g * 16 + quad * 4 + 0) * OSTR + dt * 16 + q15];\
            oacc[g][dt].y += b[(g * 16 + quad * 4 + 1) * OSTR + dt * 16 + q15];\
            oacc[g][dt].z += b[(g * 16 + quad * 4 + 2) * OSTR + dt * 16 + q15];\
            oacc[g][dt].w += b[(g * 16 + quad * 4 + 3) * OSTR + dt * 16 + q15];\
        }                                                                    \
    }
    if (w >= 4) OWRITE(w - 4);
    __syncthreads();
    if (w < 4) OADD(w);
    __syncthreads();
    if (w == 2 || w == 3) OWRITE(w - 2);
    __syncthreads();
    if (w < 2) OADD(w);
    __syncthreads();
    if (w < 2) OWRITE(w);
    __syncthreads();

    {
        const int q  = t >> 3;            // 0..63
        const int d0 = (t & 7) * 8;
        float l = 0.f;
#pragma unroll
        for (int i = 0; i < 8; ++i) l += aF[20480 + i * 64 + q];
        const float linv = 1.0f / l;
#pragma unroll
        for (int k2 = 0; k2 < 2; ++k2) {
            float4 a = *(const float4*)&aF[q * OSTR + d0 + k2 * 4];
            float4 b = *(const float4*)&aF[OBUF + q * OSTR + d0 + k2 * 4];
            float4 s;
            s.x = (a.x + b.x) * linv; s.y = (a.y + b.y) * linv;
            s.z = (a.z + b.z) * linv; s.w = (a.w + b.w) * linv;
            *(float4*)(out + (base + q0 + q) * 64 + d0 + k2 * 4) = s;
        }
    }
}

// ---------------------------------------------------------------------------
extern "C" void kernel_launch(void* const* d_in, const int* in_sizes, int n_in,
                              void* d_out, int out_size, void* d_ws, size_t ws_size,
                              hipStream_t stream)
{
    const float* ix = (const float*)d_in[0];
    const float* Wk = (const float*)d_in[1];
    const float* Wq = (const float*)d_in[2];
    const float* Wv = (const float*)d_in[3];
    float* out = (float*)d_out;

    // ws: Qw | Kt | Vt (NROW*64 ushorts each) + WTt (24*192*32 ushorts)
    ushort* Qw  = (ushort*)d_ws;
    ushort* Kt  = Qw + (size_t)NROW * Hm;
    ushort* Vt  = Kt + (size_t)NROW * Hm;
    ushort* WTt = Vt + (size_t)NROW * Hm;

    wconv<<<72, 256, 0, stream>>>(Wq, Wk, Wv, WTt);
    proj<<<512, 256, 0, stream>>>(ix, WTt, Qw, Kt, Vt);
    attn<<<256, 512, 0, stream>>>(Qw, Kt, Vt, out);
}